// Round 1
// baseline (4683.113 us; speedup 1.0000x reference)
//
#include <hip/hip_runtime.h>

// 2-layer GCNConv, N=500K, E=16M, Cin=1, Cout=4, fp32.
// Pipeline:
//   memset deg/S/U -> k_deg -> k_node1 (dinv,y) -> k_scatter1 (S += y[src])
//   -> k_node2 (h=relu(...), g=dinv*(h@W2)) -> k_scatter2 (U += g[src])
//   -> k_node3 (out = b2 + dinv*(U+g))

#define THREADS 256

__global__ __launch_bounds__(THREADS) void k_deg(
    const int* __restrict__ dst, int n4, int tail, int* __restrict__ deg) {
  int t = blockIdx.x * blockDim.x + threadIdx.x;
  if (t < n4) {
    int4 d = reinterpret_cast<const int4*>(dst)[t];
    atomicAdd(&deg[d.x], 1);
    atomicAdd(&deg[d.y], 1);
    atomicAdd(&deg[d.z], 1);
    atomicAdd(&deg[d.w], 1);
  } else if (t - n4 < tail) {
    atomicAdd(&deg[dst[4 * n4 + (t - n4)]], 1);
  }
}

__global__ __launch_bounds__(THREADS) void k_node1(
    const float* __restrict__ x, const int* __restrict__ deg,
    float* __restrict__ dinv, float* __restrict__ y, int n) {
  int i = blockIdx.x * blockDim.x + threadIdx.x;
  if (i < n) {
    float d = (float)deg[i] + 1.0f;  // +1 self-loop
    float r = rsqrtf(d);
    dinv[i] = r;
    y[i] = r * x[i];
  }
}

__global__ __launch_bounds__(THREADS) void k_scatter1(
    const int* __restrict__ src, const int* __restrict__ dst, int n4, int tail,
    const float* __restrict__ y, float* __restrict__ S) {
  int t = blockIdx.x * blockDim.x + threadIdx.x;
  if (t < n4) {
    int4 s = reinterpret_cast<const int4*>(src)[t];
    int4 d = reinterpret_cast<const int4*>(dst)[t];
    unsafeAtomicAdd(&S[d.x], y[s.x]);
    unsafeAtomicAdd(&S[d.y], y[s.y]);
    unsafeAtomicAdd(&S[d.z], y[s.z]);
    unsafeAtomicAdd(&S[d.w], y[s.w]);
  } else if (t - n4 < tail) {
    int e = 4 * n4 + (t - n4);
    unsafeAtomicAdd(&S[dst[e]], y[src[e]]);
  }
}

__global__ __launch_bounds__(THREADS) void k_node2(
    const float* __restrict__ S, const float* __restrict__ y,
    const float* __restrict__ dinv,
    const float* __restrict__ W1, const float* __restrict__ b1,
    const float* __restrict__ W2,
    float4* __restrict__ g, int n) {
  int i = blockIdx.x * blockDim.x + threadIdx.x;
  if (i < n) {
    float r = dinv[i];
    float s = r * (S[i] + y[i]);  // dinv[i]*(edge sum + self-loop)
    float h0 = fmaxf(fmaf(s, W1[0], b1[0]), 0.0f);
    float h1 = fmaxf(fmaf(s, W1[1], b1[1]), 0.0f);
    float h2 = fmaxf(fmaf(s, W1[2], b1[2]), 0.0f);
    float h3 = fmaxf(fmaf(s, W1[3], b1[3]), 0.0f);
    float g0 = h0 * W2[0] + h1 * W2[4] + h2 * W2[8]  + h3 * W2[12];
    float g1 = h0 * W2[1] + h1 * W2[5] + h2 * W2[9]  + h3 * W2[13];
    float g2 = h0 * W2[2] + h1 * W2[6] + h2 * W2[10] + h3 * W2[14];
    float g3 = h0 * W2[3] + h1 * W2[7] + h2 * W2[11] + h3 * W2[15];
    g[i] = make_float4(r * g0, r * g1, r * g2, r * g3);
  }
}

__global__ __launch_bounds__(THREADS) void k_scatter2(
    const int* __restrict__ src, const int* __restrict__ dst, int n4, int tail,
    const float4* __restrict__ g, float* __restrict__ U) {
  int t = blockIdx.x * blockDim.x + threadIdx.x;
  if (t < n4) {
    int4 s = reinterpret_cast<const int4*>(src)[t];
    int4 d = reinterpret_cast<const int4*>(dst)[t];
    float4 g0 = g[s.x];
    float4 g1 = g[s.y];
    float4 g2 = g[s.z];
    float4 g3 = g[s.w];
    float* u0 = U + 4 * (long long)d.x;
    unsafeAtomicAdd(u0 + 0, g0.x); unsafeAtomicAdd(u0 + 1, g0.y);
    unsafeAtomicAdd(u0 + 2, g0.z); unsafeAtomicAdd(u0 + 3, g0.w);
    float* u1 = U + 4 * (long long)d.y;
    unsafeAtomicAdd(u1 + 0, g1.x); unsafeAtomicAdd(u1 + 1, g1.y);
    unsafeAtomicAdd(u1 + 2, g1.z); unsafeAtomicAdd(u1 + 3, g1.w);
    float* u2 = U + 4 * (long long)d.z;
    unsafeAtomicAdd(u2 + 0, g2.x); unsafeAtomicAdd(u2 + 1, g2.y);
    unsafeAtomicAdd(u2 + 2, g2.z); unsafeAtomicAdd(u2 + 3, g2.w);
    float* u3 = U + 4 * (long long)d.w;
    unsafeAtomicAdd(u3 + 0, g3.x); unsafeAtomicAdd(u3 + 1, g3.y);
    unsafeAtomicAdd(u3 + 2, g3.z); unsafeAtomicAdd(u3 + 3, g3.w);
  } else if (t - n4 < tail) {
    int e = 4 * n4 + (t - n4);
    float4 gv = g[src[e]];
    float* u = U + 4 * (long long)dst[e];
    unsafeAtomicAdd(u + 0, gv.x); unsafeAtomicAdd(u + 1, gv.y);
    unsafeAtomicAdd(u + 2, gv.z); unsafeAtomicAdd(u + 3, gv.w);
  }
}

__global__ __launch_bounds__(THREADS) void k_node3(
    const float4* __restrict__ U, const float4* __restrict__ g,
    const float* __restrict__ dinv, const float* __restrict__ b2,
    float4* __restrict__ out, int n) {
  int i = blockIdx.x * blockDim.x + threadIdx.x;
  if (i < n) {
    float r = dinv[i];
    float4 u = U[i];
    float4 gv = g[i];
    out[i] = make_float4(b2[0] + r * (u.x + gv.x),
                         b2[1] + r * (u.y + gv.y),
                         b2[2] + r * (u.z + gv.z),
                         b2[3] + r * (u.w + gv.w));
  }
}

extern "C" void kernel_launch(void* const* d_in, const int* in_sizes, int n_in,
                              void* d_out, int out_size, void* d_ws, size_t ws_size,
                              hipStream_t stream) {
  const float* x  = (const float*)d_in[0];
  const int*   ei = (const int*)d_in[1];
  const float* W1 = (const float*)d_in[2];
  const float* b1 = (const float*)d_in[3];
  const float* W2 = (const float*)d_in[4];
  const float* b2 = (const float*)d_in[5];

  const int n = in_sizes[0];       // Cin == 1 -> x has N elements
  const int E = in_sizes[1] / 2;   // edge_index is [2, E] int32
  const int* src = ei;
  const int* dst = ei + E;

  // Workspace layout (16B-aligned slabs)
  size_t nb1 = ((size_t)n * 4 + 255) & ~(size_t)255;   // n floats/ints
  size_t nb4 = ((size_t)n * 16 + 255) & ~(size_t)255;  // n float4
  char* p = (char*)d_ws;
  int*    deg  = (int*)p;             p += nb1;
  float*  dinv = (float*)p;           p += nb1;
  float*  y    = (float*)p;           p += nb1;
  float*  S    = (float*)p;           p += nb1;
  float4* g    = (float4*)p;          p += nb4;
  float*  U    = (float*)p;           p += nb4;

  // Zero accumulators (workspace is poisoned before every call)
  hipMemsetAsync(deg, 0, (size_t)n * 4, stream);
  hipMemsetAsync(S,   0, (size_t)n * 4, stream);
  hipMemsetAsync(U,   0, (size_t)n * 16, stream);

  const int n4 = E / 4;
  const int tail = E - 4 * n4;
  const int edge_threads = n4 + tail;
  const int eb = (edge_threads + THREADS - 1) / THREADS;
  const int nblk = (n + THREADS - 1) / THREADS;

  k_deg<<<eb, THREADS, 0, stream>>>(dst, n4, tail, deg);
  k_node1<<<nblk, THREADS, 0, stream>>>(x, deg, dinv, y, n);
  k_scatter1<<<eb, THREADS, 0, stream>>>(src, dst, n4, tail, y, S);
  k_node2<<<nblk, THREADS, 0, stream>>>(S, y, dinv, W1, b1, W2, g, n);
  k_scatter2<<<eb, THREADS, 0, stream>>>(src, dst, n4, tail, g, U);
  k_node3<<<nblk, THREADS, 0, stream>>>((const float4*)U, g, dinv, b2,
                                        (float4*)d_out, n);
}

// Round 2
// 4621.354 us; speedup vs baseline: 1.0134x; 1.0134x over previous
//
#include <hip/hip_runtime.h>

// 2-layer GCNConv, N=500K, E=16M, Cin=1, Cout=4, fp32.
//
// Key idea this round: device-scope fp32 atomics on gfx950 write through to
// the memory side (measured: WRITE_SIZE == 64M atomics * 32B, ~20G atomics/s).
// Instead, give each XCD its own accumulator replica (selected via
// HW_REG_XCC_ID) and use plain global_atomic_add_f32 (no sc1) so the atomic
// executes in the XCD-local L2. Replicas are summed in the next kernel;
// end-of-dispatch release makes the dirty L2 lines visible stream-order.
// Layer-2 accumulators are component-split (4 passes) so each pass's dirty
// replica is 2MB and stays resident in the 4MB per-XCD L2.

#define THREADS 256

__device__ __forceinline__ int xcc_id() {
  int x;
  asm("s_getreg_b32 %0, hwreg(HW_REG_XCC_ID)" : "=s"(x));
  return x & 7;
}

template <bool LOCAL>
__device__ __forceinline__ void at_add(float* p, float v) {
  if constexpr (LOCAL)
    asm volatile("global_atomic_add_f32 %0, %1, off" ::"v"(p), "v"(v) : "memory");
  else
    unsafeAtomicAdd(p, v);
}

template <bool LOCAL>
__device__ __forceinline__ void at_add(int* p, int v) {
  if constexpr (LOCAL)
    asm volatile("global_atomic_add %0, %1, off" ::"v"(p), "v"(v) : "memory");
  else
    atomicAdd(p, v);
}

// ---- degree count (dst only) ----
template <bool LOCAL>
__global__ __launch_bounds__(THREADS) void k_deg(
    const int* __restrict__ dst, int n4, int tail, int* __restrict__ deg, int n) {
  int* dg = deg + (LOCAL ? (size_t)xcc_id() * n : 0);
  int t = blockIdx.x * blockDim.x + threadIdx.x;
  if (t < n4) {
    int4 d = reinterpret_cast<const int4*>(dst)[t];
    at_add<LOCAL>(&dg[d.x], 1);
    at_add<LOCAL>(&dg[d.y], 1);
    at_add<LOCAL>(&dg[d.z], 1);
    at_add<LOCAL>(&dg[d.w], 1);
  } else if (t - n4 < tail) {
    at_add<LOCAL>(&dg[dst[4 * n4 + (t - n4)]], 1);
  }
}

// ---- dinv, y = dinv*x ----
template <int R>
__global__ __launch_bounds__(THREADS) void k_node1(
    const float* __restrict__ x, const int* __restrict__ deg,
    float* __restrict__ dinv, float* __restrict__ y, int n) {
  int i = blockIdx.x * blockDim.x + threadIdx.x;
  if (i < n) {
    int d = 1;  // self-loop
#pragma unroll
    for (int r = 0; r < R; ++r) d += deg[(size_t)r * n + i];
    float rr = rsqrtf((float)d);
    dinv[i] = rr;
    y[i] = rr * x[i];
  }
}

// ---- layer-1 scatter: S += y[src] at dst ----
template <bool LOCAL>
__global__ __launch_bounds__(THREADS) void k_scatter1(
    const int* __restrict__ src, const int* __restrict__ dst, int n4, int tail,
    const float* __restrict__ y, float* __restrict__ S, int n) {
  float* Sr = S + (LOCAL ? (size_t)xcc_id() * n : 0);
  int t = blockIdx.x * blockDim.x + threadIdx.x;
  if (t < n4) {
    int4 s = reinterpret_cast<const int4*>(src)[t];
    int4 d = reinterpret_cast<const int4*>(dst)[t];
    at_add<LOCAL>(&Sr[d.x], y[s.x]);
    at_add<LOCAL>(&Sr[d.y], y[s.y]);
    at_add<LOCAL>(&Sr[d.z], y[s.z]);
    at_add<LOCAL>(&Sr[d.w], y[s.w]);
  } else if (t - n4 < tail) {
    int e = 4 * n4 + (t - n4);
    at_add<LOCAL>(&Sr[dst[e]], y[src[e]]);
  }
}

// ---- layer-1 epilogue + layer-2 linear: g (SoA, 4 planes of n floats) ----
template <int R>
__global__ __launch_bounds__(THREADS) void k_node2(
    const float* __restrict__ S, const float* __restrict__ y,
    const float* __restrict__ dinv,
    const float* __restrict__ W1, const float* __restrict__ b1,
    const float* __restrict__ W2,
    float* __restrict__ g, int n) {
  int i = blockIdx.x * blockDim.x + threadIdx.x;
  if (i < n) {
    float ssum = y[i];  // self-loop message
#pragma unroll
    for (int r = 0; r < R; ++r) ssum += S[(size_t)r * n + i];
    float rr = dinv[i];
    float s = rr * ssum;
    float h0 = fmaxf(fmaf(s, W1[0], b1[0]), 0.0f);
    float h1 = fmaxf(fmaf(s, W1[1], b1[1]), 0.0f);
    float h2 = fmaxf(fmaf(s, W1[2], b1[2]), 0.0f);
    float h3 = fmaxf(fmaf(s, W1[3], b1[3]), 0.0f);
    g[0 * (size_t)n + i] = rr * (h0 * W2[0] + h1 * W2[4] + h2 * W2[8]  + h3 * W2[12]);
    g[1 * (size_t)n + i] = rr * (h0 * W2[1] + h1 * W2[5] + h2 * W2[9]  + h3 * W2[13]);
    g[2 * (size_t)n + i] = rr * (h0 * W2[2] + h1 * W2[6] + h2 * W2[10] + h3 * W2[14]);
    g[3 * (size_t)n + i] = rr * (h0 * W2[3] + h1 * W2[7] + h2 * W2[11] + h3 * W2[15]);
  }
}

// ---- layer-2 scatter, one component plane per launch ----
template <bool LOCAL>
__global__ __launch_bounds__(THREADS) void k_scatter2(
    const int* __restrict__ src, const int* __restrict__ dst, int n4, int tail,
    const float* __restrict__ gc, float* __restrict__ Uc, int n) {
  float* Ur = Uc + (LOCAL ? (size_t)xcc_id() * n : 0);
  int t = blockIdx.x * blockDim.x + threadIdx.x;
  if (t < n4) {
    int4 s = reinterpret_cast<const int4*>(src)[t];
    int4 d = reinterpret_cast<const int4*>(dst)[t];
    at_add<LOCAL>(&Ur[d.x], gc[s.x]);
    at_add<LOCAL>(&Ur[d.y], gc[s.y]);
    at_add<LOCAL>(&Ur[d.z], gc[s.z]);
    at_add<LOCAL>(&Ur[d.w], gc[s.w]);
  } else if (t - n4 < tail) {
    int e = 4 * n4 + (t - n4);
    at_add<LOCAL>(&Ur[dst[e]], gc[src[e]]);
  }
}

// ---- final epilogue: out = b2 + dinv*(U_sum + g_self) ----
template <int R>
__global__ __launch_bounds__(THREADS) void k_node3(
    const float* __restrict__ U, const float* __restrict__ g,
    const float* __restrict__ dinv, const float* __restrict__ b2,
    float4* __restrict__ out, int n) {
  int i = blockIdx.x * blockDim.x + threadIdx.x;
  if (i < n) {
    float rr = dinv[i];
    float o[4];
#pragma unroll
    for (int c = 0; c < 4; ++c) {
      float u = g[(size_t)c * n + i];  // self-loop message
#pragma unroll
      for (int r = 0; r < R; ++r) u += U[((size_t)c * R + r) * n + i];
      o[c] = b2[c] + rr * u;
    }
    out[i] = make_float4(o[0], o[1], o[2], o[3]);
  }
}

extern "C" void kernel_launch(void* const* d_in, const int* in_sizes, int n_in,
                              void* d_out, int out_size, void* d_ws, size_t ws_size,
                              hipStream_t stream) {
  const float* x  = (const float*)d_in[0];
  const int*   ei = (const int*)d_in[1];
  const float* W1 = (const float*)d_in[2];
  const float* b1 = (const float*)d_in[3];
  const float* W2 = (const float*)d_in[4];
  const float* b2 = (const float*)d_in[5];

  const int n = in_sizes[0];      // Cin == 1 -> x has N elements
  const int E = in_sizes[1] / 2;  // edge_index is [2, E]
  const int* src = ei;
  const int* dst = ei + E;

  const size_t nn = (size_t)n;
  auto al = [](size_t v) { return (v + 255) & ~(size_t)255; };

  const int n4 = E / 4;
  const int tail = E - 4 * n4;
  const int edge_threads = n4 + tail;
  const int eb = (edge_threads + THREADS - 1) / THREADS;
  const int nblk = (n + THREADS - 1) / THREADS;

  // Replicated (per-XCD) layout: R=8
  {
    const int R = 8;
    size_t sz_deg = al(nn * 4 * R);
    size_t sz_S   = al(nn * 4 * R);
    size_t sz_U   = al(nn * 4 * R * 4);
    size_t sz_g   = al(nn * 4 * 4);
    size_t sz_dv  = al(nn * 4);
    size_t sz_y   = al(nn * 4);
    size_t need = sz_deg + sz_S + sz_U + sz_g + sz_dv + sz_y;
    if (ws_size >= need) {
      char* p = (char*)d_ws;
      int*   deg  = (int*)p;    p += sz_deg;
      float* S    = (float*)p;  p += sz_S;
      float* U    = (float*)p;  p += sz_U;
      float* g    = (float*)p;  p += sz_g;
      float* dinv = (float*)p;  p += sz_dv;
      float* y    = (float*)p;  p += sz_y;

      hipMemsetAsync(deg, 0, sz_deg + sz_S + sz_U, stream);

      k_deg<true><<<eb, THREADS, 0, stream>>>(dst, n4, tail, deg, n);
      k_node1<R><<<nblk, THREADS, 0, stream>>>(x, deg, dinv, y, n);
      k_scatter1<true><<<eb, THREADS, 0, stream>>>(src, dst, n4, tail, y, S, n);
      k_node2<R><<<nblk, THREADS, 0, stream>>>(S, y, dinv, W1, b1, W2, g, n);
#pragma unroll
      for (int c = 0; c < 4; ++c) {
        k_scatter2<true><<<eb, THREADS, 0, stream>>>(
            src, dst, n4, tail, g + (size_t)c * nn, U + (size_t)c * R * nn, n);
      }
      k_node3<R><<<nblk, THREADS, 0, stream>>>(U, g, dinv, b2, (float4*)d_out, n);
      return;
    }
  }

  // Fallback: single copy, device-scope atomics (previous round's behavior)
  {
    const int R = 1;
    size_t sz_deg = al(nn * 4);
    size_t sz_S   = al(nn * 4);
    size_t sz_U   = al(nn * 4 * 4);
    size_t sz_g   = al(nn * 4 * 4);
    size_t sz_dv  = al(nn * 4);
    size_t sz_y   = al(nn * 4);
    char* p = (char*)d_ws;
    int*   deg  = (int*)p;    p += sz_deg;
    float* S    = (float*)p;  p += sz_S;
    float* U    = (float*)p;  p += sz_U;
    float* g    = (float*)p;  p += sz_g;
    float* dinv = (float*)p;  p += sz_dv;
    float* y    = (float*)p;  p += sz_y;

    hipMemsetAsync(deg, 0, sz_deg + sz_S + sz_U, stream);

    k_deg<false><<<eb, THREADS, 0, stream>>>(dst, n4, tail, deg, n);
    k_node1<R><<<nblk, THREADS, 0, stream>>>(x, deg, dinv, y, n);
    k_scatter1<false><<<eb, THREADS, 0, stream>>>(src, dst, n4, tail, y, S, n);
    k_node2<R><<<nblk, THREADS, 0, stream>>>(S, y, dinv, W1, b1, W2, g, n);
    for (int c = 0; c < 4; ++c) {
      k_scatter2<false><<<eb, THREADS, 0, stream>>>(
          src, dst, n4, tail, g + (size_t)c * nn, U + (size_t)c * nn, n);
    }
    k_node3<R><<<nblk, THREADS, 0, stream>>>(U, g, dinv, b2, (float4*)d_out, n);
  }
}

// Round 3
// 1063.989 us; speedup vs baseline: 4.4015x; 4.3434x over previous
//
#include <hip/hip_runtime.h>

// 2-layer GCNConv, N=500K, E=16M, Cin=1, Cout=4, fp32.
//
// Round-2 finding: fp32/int global atomics on gfx950 execute memory-side,
// 32 B write per atomic, ~20.7 G atomics/s ceiling (WRITE_SIZE == ops*32B,
// identical for unsafeAtomicAdd and plain global_atomic_add_f32). 96M atomic
// ops == 4.6 ms. This round eliminates per-edge global atomics entirely:
//   k_bin        : bucket edges by dst>>8 (256 nodes/bucket). Per-block LDS
//                  histogram + ONE global fetch-add per (block,bucket) range
//                  reservation (~500K atomics total). Payload (src<<8|dstlo)
//                  written with normal cached stores; ranges padded to 64 B
//                  so no cache line has two writer blocks (pad = -1 sentinel).
//   k_deg_node1  : per-bucket degree count in LDS -> dinv, y = dinv*x.
//   k_reduce1    : gather y[src], ds_add into LDS, emit (dinv_i, s_i).
//   k_reduce2    : layer-1 out per node = s_i*W1 + b1 (scalar s_i!); via
//                  relu(z)=(z+|z|)/2 the layer-2 message is an exact linear
//                  combo of 6 per-edge scalars {dinv, dinv*s, dinv*|s-t_c|},
//                  t_c = -b1_c/W1_c. 6 LDS ds_adds/edge, exact for any b1/b2.

#define BIN_BLOCKS 256
#define BIN_THREADS 1024
#define PAD 16           // pad reservations to 16 slots = 64 B lines
#define MAXNB 2048       // supports n <= 524288

__global__ __launch_bounds__(BIN_THREADS) void k_bin(
    const int* __restrict__ src, const int* __restrict__ dst, int E,
    int chunk, int nb, int C, int* __restrict__ gcur,
    int* __restrict__ payload) {
  __shared__ int hist[MAXNB];
  __shared__ int lbase[MAXNB];
  const int tid = threadIdx.x;
  const long long e0 = (long long)blockIdx.x * chunk;
  long long rem = (long long)E - e0;
  int lim = rem < 0 ? 0 : (rem < chunk ? (int)rem : chunk);

  for (int j = tid; j < nb; j += BIN_THREADS) hist[j] = 0;
  __syncthreads();

  const int* dch = dst + e0;
  const int* sch = src + e0;
  const int nv = lim >> 2;

  // pass 1: local histogram (LDS atomics)
  for (int k = tid; k < nv; k += BIN_THREADS) {
    int4 d = reinterpret_cast<const int4*>(dch)[k];
    atomicAdd(&hist[d.x >> 8], 1);
    atomicAdd(&hist[d.y >> 8], 1);
    atomicAdd(&hist[d.z >> 8], 1);
    atomicAdd(&hist[d.w >> 8], 1);
  }
  for (int k = (nv << 2) + tid; k < lim; k += BIN_THREADS)
    atomicAdd(&hist[dch[k] >> 8], 1);
  __syncthreads();

  // reserve padded ranges: one global fetch-add per (block,bucket)
  for (int j = tid; j < nb; j += BIN_THREADS) {
    int c = hist[j];
    lbase[j] = c ? atomicAdd(&gcur[j], (c + PAD - 1) & ~(PAD - 1)) : 0;
    hist[j] = 0;  // reuse as local rank cursor
  }
  __syncthreads();

  // pass 2: place edges (normal cached stores)
  for (int k = tid; k < nv; k += BIN_THREADS) {
    int4 d = reinterpret_cast<const int4*>(dch)[k];
    int4 s = reinterpret_cast<const int4*>(sch)[k];
    int bk, r;
    bk = d.x >> 8; r = atomicAdd(&hist[bk], 1) + lbase[bk];
    if (r < C) payload[(long long)bk * C + r] = (s.x << 8) | (d.x & 255);
    bk = d.y >> 8; r = atomicAdd(&hist[bk], 1) + lbase[bk];
    if (r < C) payload[(long long)bk * C + r] = (s.y << 8) | (d.y & 255);
    bk = d.z >> 8; r = atomicAdd(&hist[bk], 1) + lbase[bk];
    if (r < C) payload[(long long)bk * C + r] = (s.z << 8) | (d.z & 255);
    bk = d.w >> 8; r = atomicAdd(&hist[bk], 1) + lbase[bk];
    if (r < C) payload[(long long)bk * C + r] = (s.w << 8) | (d.w & 255);
  }
  for (int k = (nv << 2) + tid; k < lim; k += BIN_THREADS) {
    int d = dch[k], s = sch[k];
    int bk = d >> 8;
    int r = atomicAdd(&hist[bk], 1) + lbase[bk];
    if (r < C) payload[(long long)bk * C + r] = (s << 8) | (d & 255);
  }
  __syncthreads();

  // sentinel-fill pad slots of this block's ranges
  for (int j = tid; j < nb; j += BIN_THREADS) {
    int c = hist[j];
    if (c) {
      int pc = (c + PAD - 1) & ~(PAD - 1);
      long long base = (long long)j * C;
      for (int k = lbase[j] + c; k < lbase[j] + pc; ++k)
        if (k < C) payload[base + k] = -1;
    }
  }
}

__global__ __launch_bounds__(256) void k_deg_node1(
    const int* __restrict__ payload, const int* __restrict__ gcur, int C,
    int n, const float* __restrict__ x, float* __restrict__ dinv,
    float* __restrict__ y) {
  __shared__ int cnt[256];
  const int b = blockIdx.x, tid = threadIdx.x;
  cnt[tid] = 0;
  __syncthreads();
  const int L = min(gcur[b], C);
  const int* seg = payload + (long long)b * C;
  const int nv = L >> 2;
  for (int k = tid; k < nv; k += 256) {
    int4 p = reinterpret_cast<const int4*>(seg)[k];
    if (p.x >= 0) atomicAdd(&cnt[p.x & 255], 1);
    if (p.y >= 0) atomicAdd(&cnt[p.y & 255], 1);
    if (p.z >= 0) atomicAdd(&cnt[p.z & 255], 1);
    if (p.w >= 0) atomicAdd(&cnt[p.w & 255], 1);
  }
  for (int k = (nv << 2) + tid; k < L; k += 256) {
    int p = seg[k];
    if (p >= 0) atomicAdd(&cnt[p & 255], 1);
  }
  __syncthreads();
  const int i = (b << 8) + tid;
  if (i < n) {
    float r = rsqrtf((float)(cnt[tid] + 1));  // +1 self-loop
    dinv[i] = r;
    y[i] = r * x[i];
  }
}

__global__ __launch_bounds__(256) void k_reduce1(
    const int* __restrict__ payload, const int* __restrict__ gcur, int C,
    int n, const float* __restrict__ y, const float* __restrict__ dinv,
    float2* __restrict__ ds) {
  __shared__ float S[256];
  const int b = blockIdx.x, tid = threadIdx.x;
  S[tid] = 0.0f;
  __syncthreads();
  const int L = min(gcur[b], C);
  const int* seg = payload + (long long)b * C;
  const int nv = L >> 2;
  for (int k = tid; k < nv; k += 256) {
    int4 p = reinterpret_cast<const int4*>(seg)[k];
    if (p.x >= 0) atomicAdd(&S[p.x & 255], y[p.x >> 8]);
    if (p.y >= 0) atomicAdd(&S[p.y & 255], y[p.y >> 8]);
    if (p.z >= 0) atomicAdd(&S[p.z & 255], y[p.z >> 8]);
    if (p.w >= 0) atomicAdd(&S[p.w & 255], y[p.w >> 8]);
  }
  for (int k = (nv << 2) + tid; k < L; k += 256) {
    int p = seg[k];
    if (p >= 0) atomicAdd(&S[p & 255], y[p >> 8]);
  }
  __syncthreads();
  const int i = (b << 8) + tid;
  if (i < n) {
    float r = dinv[i];
    float s = r * (S[tid] + y[i]);  // layer-1 scalar aggregate
    ds[i] = make_float2(r, s);
  }
}

__global__ __launch_bounds__(256) void k_reduce2(
    const int* __restrict__ payload, const int* __restrict__ gcur, int C,
    int n, const float2* __restrict__ ds,
    const float* __restrict__ W1, const float* __restrict__ b1,
    const float* __restrict__ W2, const float* __restrict__ b2,
    float4* __restrict__ out) {
  __shared__ float acc[256 * 6];
  const int b = blockIdx.x, tid = threadIdx.x;
#pragma unroll
  for (int k = 0; k < 6; ++k) acc[tid * 6 + k] = 0.0f;
  __syncthreads();

  // relu(s*W1c + b1c) = 0.5*[(s*W1c + b1c) + |W1c|*|s - t_c|], t_c = -b1c/W1c
  float t[4], m[4];
#pragma unroll
  for (int c = 0; c < 4; ++c) {
    float w = W1[c];
    if (fabsf(w) > 1e-30f) { t[c] = -b1[c] / w; m[c] = fabsf(w); }
    else                   { t[c] = 0.0f;       m[c] = 0.0f; }
  }

  const int L = min(gcur[b], C);
  const int* seg = payload + (long long)b * C;
  const int nv = L >> 2;
  auto edge = [&](int p) {
    if (p < 0) return;
    float2 v = ds[p >> 8];  // (dinv_src, s_src)
    float* a = &acc[(p & 255) * 6];
    atomicAdd(a + 0, v.x);
    atomicAdd(a + 1, v.x * v.y);
    atomicAdd(a + 2, v.x * fabsf(v.y - t[0]));
    atomicAdd(a + 3, v.x * fabsf(v.y - t[1]));
    atomicAdd(a + 4, v.x * fabsf(v.y - t[2]));
    atomicAdd(a + 5, v.x * fabsf(v.y - t[3]));
  };
  for (int k = tid; k < nv; k += 256) {
    int4 p = reinterpret_cast<const int4*>(seg)[k];
    edge(p.x); edge(p.y); edge(p.z); edge(p.w);
  }
  for (int k = (nv << 2) + tid; k < L; k += 256) edge(seg[k]);
  __syncthreads();

  const int i = (b << 8) + tid;
  if (i < n) {
    float2 v = ds[i];
    float A0 = acc[tid * 6 + 0] + v.x;            // + self-loop message
    float A1 = acc[tid * 6 + 1] + v.x * v.y;
    float B[4];
#pragma unroll
    for (int c = 0; c < 4; ++c)
      B[c] = acc[tid * 6 + 2 + c] + v.x * fabsf(v.y - t[c]);
    float o[4];
#pragma unroll
    for (int cp = 0; cp < 4; ++cp) {
      float wW2 = 0.0f, bw = 0.0f, ab = 0.0f;
#pragma unroll
      for (int c = 0; c < 4; ++c) {
        float w2 = W2[c * 4 + cp];
        wW2 += W1[c] * w2;
        bw  += b1[c] * w2;
        if (m[c] == 0.0f) bw += fabsf(b1[c]) * w2;  // |z| term for W1c==0
        else              ab += m[c] * B[c] * w2;
      }
      o[cp] = b2[cp] + v.x * 0.5f * (A1 * wW2 + A0 * bw + ab);
    }
    out[i] = make_float4(o[0], o[1], o[2], o[3]);
  }
}

extern "C" void kernel_launch(void* const* d_in, const int* in_sizes, int n_in,
                              void* d_out, int out_size, void* d_ws, size_t ws_size,
                              hipStream_t stream) {
  const float* x  = (const float*)d_in[0];
  const int*   ei = (const int*)d_in[1];
  const float* W1 = (const float*)d_in[2];
  const float* b1 = (const float*)d_in[3];
  const float* W2 = (const float*)d_in[4];
  const float* b2 = (const float*)d_in[5];

  const int n = in_sizes[0];
  const int E = in_sizes[1] / 2;
  const int* src = ei;
  const int* dst = ei + E;

  const int nb = (n + 255) >> 8;  // buckets of 256 nodes (nb <= MAXNB)
  auto al = [](size_t v) { return (v + 255) & ~(size_t)255; };

  // fixed arrays
  const size_t nn = (size_t)n;
  size_t sz_ds = al(nn * 8), sz_y = al(nn * 4), sz_dv = al(nn * 4),
         sz_gc = al((size_t)nb * 4);
  size_t fixed = sz_ds + sz_y + sz_dv + sz_gc;

  // bucket capacity: mean + pad inflation (BIN_BLOCKS*PAD/2) + 25% + slack,
  // capped by workspace budget
  double mean = (double)E / nb;
  long long Cwant = (long long)(mean * 1.25) + (long long)(BIN_BLOCKS * PAD / 2) + 512;
  size_t budget = ws_size > fixed ? ws_size - fixed - 4096 : 0;
  long long Cbud = (long long)(budget / ((size_t)nb * 4));
  long long Cll = Cwant < Cbud ? Cwant : Cbud;
  int C = (int)(Cll & ~(long long)(PAD - 1));

  char* p = (char*)d_ws;
  int*    payload = (int*)p;    p += al((size_t)nb * C * 4);
  float2* ds      = (float2*)p; p += sz_ds;
  float*  y       = (float*)p;  p += sz_y;
  float*  dinv    = (float*)p;  p += sz_dv;
  int*    gcur    = (int*)p;    p += sz_gc;

  hipMemsetAsync(gcur, 0, (size_t)nb * 4, stream);

  int chunk = (int)(((long long)E + BIN_BLOCKS - 1) / BIN_BLOCKS);
  chunk = (chunk + 3) & ~3;  // keep int4 alignment per block

  k_bin<<<BIN_BLOCKS, BIN_THREADS, 0, stream>>>(src, dst, E, chunk, nb, C,
                                                gcur, payload);
  k_deg_node1<<<nb, 256, 0, stream>>>(payload, gcur, C, n, x, dinv, y);
  k_reduce1<<<nb, 256, 0, stream>>>(payload, gcur, C, n, y, dinv, ds);
  k_reduce2<<<nb, 256, 0, stream>>>(payload, gcur, C, n, ds, W1, b1, W2, b2,
                                    (float4*)d_out);
}

// Round 4
// 870.593 us; speedup vs baseline: 5.3792x; 1.2221x over previous
//
#include <hip/hip_runtime.h>

// 2-layer GCNConv, N=500K, E=16M, Cin=1, Cout=4, fp32.
//
// Round-3 finding: reduce kernels were stall-bound (VALUBusy 1.8%) on
// per-edge LDS atomics + serialized dependent gathers (~20 CU-cyc/edge).
// This round: finish the sort to node granularity (k_sort: per-bucket LDS
// counting sort, 2 LDS atomics/edge, histogram doubles as degree) so the
// reduce kernels are atomic-free CSR segmented sums with 4-wide batched
// independent gathers accumulating in registers.
//
// Pipeline: memset gcur -> k_bin (bucket by dst>>8, range-reserved cached
// stores) -> k_sort (in-LDS counting sort to node order, writes CSR offsets
// + y = dinv*x) -> k_reduce1 (s_i -> G[i] = dinv*(relu(s*W1+b1)@W2)) ->
// k_reduce2 (out = b2 + dinv*(sum G[src] + G[i])).

#define BIN_BLOCKS 256
#define BIN_THREADS 1024
#define PAD 16           // pad reservations to 16 slots = 64 B lines
#define MAXNB 2048       // supports n <= 524288
#define SORT_STAGE 12032 // ints staged in LDS by k_sort (47 KB); C <= this

__global__ __launch_bounds__(BIN_THREADS) void k_bin(
    const int* __restrict__ src, const int* __restrict__ dst, int E,
    int chunk, int nb, int C, int* __restrict__ gcur,
    int* __restrict__ payload) {
  __shared__ int hist[MAXNB];
  __shared__ int lbase[MAXNB];
  const int tid = threadIdx.x;
  const long long e0 = (long long)blockIdx.x * chunk;
  long long rem = (long long)E - e0;
  int lim = rem < 0 ? 0 : (rem < chunk ? (int)rem : chunk);

  for (int j = tid; j < nb; j += BIN_THREADS) hist[j] = 0;
  __syncthreads();

  const int* dch = dst + e0;
  const int* sch = src + e0;
  const int nv = lim >> 2;

  // pass 1: local histogram (LDS atomics)
  for (int k = tid; k < nv; k += BIN_THREADS) {
    int4 d = reinterpret_cast<const int4*>(dch)[k];
    atomicAdd(&hist[d.x >> 8], 1);
    atomicAdd(&hist[d.y >> 8], 1);
    atomicAdd(&hist[d.z >> 8], 1);
    atomicAdd(&hist[d.w >> 8], 1);
  }
  for (int k = (nv << 2) + tid; k < lim; k += BIN_THREADS)
    atomicAdd(&hist[dch[k] >> 8], 1);
  __syncthreads();

  // reserve padded ranges: one global fetch-add per (block,bucket)
  for (int j = tid; j < nb; j += BIN_THREADS) {
    int c = hist[j];
    lbase[j] = c ? atomicAdd(&gcur[j], (c + PAD - 1) & ~(PAD - 1)) : 0;
    hist[j] = 0;  // reuse as local rank cursor
  }
  __syncthreads();

  // pass 2: place edges (normal cached stores)
  for (int k = tid; k < nv; k += BIN_THREADS) {
    int4 d = reinterpret_cast<const int4*>(dch)[k];
    int4 s = reinterpret_cast<const int4*>(sch)[k];
    int bk, r;
    bk = d.x >> 8; r = atomicAdd(&hist[bk], 1) + lbase[bk];
    if (r < C) payload[(long long)bk * C + r] = (s.x << 8) | (d.x & 255);
    bk = d.y >> 8; r = atomicAdd(&hist[bk], 1) + lbase[bk];
    if (r < C) payload[(long long)bk * C + r] = (s.y << 8) | (d.y & 255);
    bk = d.z >> 8; r = atomicAdd(&hist[bk], 1) + lbase[bk];
    if (r < C) payload[(long long)bk * C + r] = (s.z << 8) | (d.z & 255);
    bk = d.w >> 8; r = atomicAdd(&hist[bk], 1) + lbase[bk];
    if (r < C) payload[(long long)bk * C + r] = (s.w << 8) | (d.w & 255);
  }
  for (int k = (nv << 2) + tid; k < lim; k += BIN_THREADS) {
    int d = dch[k], s = sch[k];
    int bk = d >> 8;
    int r = atomicAdd(&hist[bk], 1) + lbase[bk];
    if (r < C) payload[(long long)bk * C + r] = (s << 8) | (d & 255);
  }
  __syncthreads();

  // sentinel-fill pad slots of this block's ranges
  for (int j = tid; j < nb; j += BIN_THREADS) {
    int c = hist[j];
    if (c) {
      int pc = (c + PAD - 1) & ~(PAD - 1);
      long long base = (long long)j * C;
      for (int k = lbase[j] + c; k < lbase[j] + pc; ++k)
        if (k < C) payload[base + k] = -1;
    }
  }
}

// Per-bucket in-LDS counting sort to node granularity (in-place on the
// global segment). hist == per-node degree -> also writes y = dinv*x.
__global__ __launch_bounds__(256) void k_sort(
    int* __restrict__ payload, const int* __restrict__ gcur, int C,
    int n, const float* __restrict__ x,
    int* __restrict__ off_g, float* __restrict__ y) {
  __shared__ int stage[SORT_STAGE];
  __shared__ int hist[256];
  __shared__ int sbuf[2][256];
  __shared__ int cur[256];
  const int b = blockIdx.x, t = threadIdx.x;
  hist[t] = 0;
  __syncthreads();

  int* seg = payload + (long long)b * C;
  const int L = min(gcur[b], C);
  const int nv = L >> 2;

  // stage segment into LDS + build per-node histogram
  for (int k = t; k < nv; k += 256) {
    int4 p = reinterpret_cast<const int4*>(seg)[k];
    reinterpret_cast<int4*>(stage)[k] = p;
    if (p.x >= 0) atomicAdd(&hist[p.x & 255], 1);
    if (p.y >= 0) atomicAdd(&hist[p.y & 255], 1);
    if (p.z >= 0) atomicAdd(&hist[p.z & 255], 1);
    if (p.w >= 0) atomicAdd(&hist[p.w & 255], 1);
  }
  for (int k = (nv << 2) + t; k < L; k += 256) {
    int p = seg[k];
    stage[k] = p;
    if (p >= 0) atomicAdd(&hist[p & 255], 1);
  }
  __syncthreads();

  // exclusive scan of hist (Hillis-Steele, double buffer)
  sbuf[0][t] = hist[t];
  __syncthreads();
  int pi = 0;
  for (int d = 1; d < 256; d <<= 1) {
    int v = sbuf[pi][t];
    if (t >= d) v += sbuf[pi][t - d];
    sbuf[pi ^ 1][t] = v;
    pi ^= 1;
    __syncthreads();
  }
  const int inc = sbuf[pi][t];
  const int exc = inc - hist[t];
  cur[t] = exc;
  off_g[b * 257 + t] = exc;
  if (t == 255) off_g[b * 257 + 256] = inc;

  const int i = (b << 8) + t;
  if (i < n) y[i] = rsqrtf((float)(hist[t] + 1)) * x[i];
  __syncthreads();

  // place: node-sorted src indices back into the global segment
  for (int k = t; k < L; k += 256) {
    int p = stage[k];
    if (p >= 0) {
      int pos = atomicAdd(&cur[p & 255], 1);
      seg[pos] = p >> 8;
    }
  }
}

// thread = node; atomic-free register sum of y[src] over CSR run;
// emit G[i] = dinv_i * (relu(s_i*W1 + b1) @ W2).
__global__ __launch_bounds__(256) void k_reduce1(
    const int* __restrict__ payload, const int* __restrict__ off_g, int C,
    int n, const float* __restrict__ y,
    const float* __restrict__ W1, const float* __restrict__ b1,
    const float* __restrict__ W2, float4* __restrict__ G) {
  const int b = blockIdx.x, t = threadIdx.x;
  const int o0 = off_g[b * 257 + t];
  const int o1 = off_g[b * 257 + t + 1];
  const int* seg = payload + (long long)b * C;
  float s = 0.0f;
  int k = o0;
  for (; k + 4 <= o1; k += 4) {
    int a0 = seg[k], a1 = seg[k + 1], a2 = seg[k + 2], a3 = seg[k + 3];
    float v0 = y[a0], v1 = y[a1], v2 = y[a2], v3 = y[a3];  // batched gathers
    s += (v0 + v1) + (v2 + v3);
  }
  for (; k < o1; ++k) s += y[seg[k]];

  const int i = (b << 8) + t;
  if (i < n) {
    float r = rsqrtf((float)(o1 - o0 + 1));
    float si = r * (s + y[i]);  // + self-loop
    float h0 = fmaxf(fmaf(si, W1[0], b1[0]), 0.0f);
    float h1 = fmaxf(fmaf(si, W1[1], b1[1]), 0.0f);
    float h2 = fmaxf(fmaf(si, W1[2], b1[2]), 0.0f);
    float h3 = fmaxf(fmaf(si, W1[3], b1[3]), 0.0f);
    G[i] = make_float4(
        r * (h0 * W2[0] + h1 * W2[4] + h2 * W2[8]  + h3 * W2[12]),
        r * (h0 * W2[1] + h1 * W2[5] + h2 * W2[9]  + h3 * W2[13]),
        r * (h0 * W2[2] + h1 * W2[6] + h2 * W2[10] + h3 * W2[14]),
        r * (h0 * W2[3] + h1 * W2[7] + h2 * W2[11] + h3 * W2[15]));
  }
}

// thread = node; atomic-free float4 register sum of G[src];
// out = b2 + dinv * (sum + G[i]).
__global__ __launch_bounds__(256) void k_reduce2(
    const int* __restrict__ payload, const int* __restrict__ off_g, int C,
    int n, const float4* __restrict__ G, const float* __restrict__ b2,
    float4* __restrict__ out) {
  const int b = blockIdx.x, t = threadIdx.x;
  const int o0 = off_g[b * 257 + t];
  const int o1 = off_g[b * 257 + t + 1];
  const int* seg = payload + (long long)b * C;
  float ax = 0.0f, ay = 0.0f, az = 0.0f, aw = 0.0f;
  int k = o0;
  for (; k + 4 <= o1; k += 4) {
    int a0 = seg[k], a1 = seg[k + 1], a2 = seg[k + 2], a3 = seg[k + 3];
    float4 g0 = G[a0], g1 = G[a1], g2 = G[a2], g3 = G[a3];  // batched
    ax += (g0.x + g1.x) + (g2.x + g3.x);
    ay += (g0.y + g1.y) + (g2.y + g3.y);
    az += (g0.z + g1.z) + (g2.z + g3.z);
    aw += (g0.w + g1.w) + (g2.w + g3.w);
  }
  for (; k < o1; ++k) {
    float4 g = G[seg[k]];
    ax += g.x; ay += g.y; az += g.z; aw += g.w;
  }

  const int i = (b << 8) + t;
  if (i < n) {
    float r = rsqrtf((float)(o1 - o0 + 1));
    float4 gi = G[i];
    out[i] = make_float4(b2[0] + r * (ax + gi.x),
                         b2[1] + r * (ay + gi.y),
                         b2[2] + r * (az + gi.z),
                         b2[3] + r * (aw + gi.w));
  }
}

extern "C" void kernel_launch(void* const* d_in, const int* in_sizes, int n_in,
                              void* d_out, int out_size, void* d_ws, size_t ws_size,
                              hipStream_t stream) {
  const float* x  = (const float*)d_in[0];
  const int*   ei = (const int*)d_in[1];
  const float* W1 = (const float*)d_in[2];
  const float* b1 = (const float*)d_in[3];
  const float* W2 = (const float*)d_in[4];
  const float* b2 = (const float*)d_in[5];

  const int n = in_sizes[0];
  const int E = in_sizes[1] / 2;
  const int* src = ei;
  const int* dst = ei + E;

  const int nb = (n + 255) >> 8;  // buckets of 256 nodes (nb <= MAXNB)
  auto al = [](size_t v) { return (v + 255) & ~(size_t)255; };

  const size_t nn = (size_t)n;
  size_t sz_off = al((size_t)nb * 257 * 4);
  size_t sz_y   = al(nn * 4);
  size_t sz_G   = al(nn * 16);
  size_t sz_gc  = al((size_t)nb * 4);
  size_t fixed = sz_off + sz_y + sz_G + sz_gc;

  // bucket capacity: mean + expected pad inflation + slack, capped by
  // workspace budget and the k_sort LDS stage capacity
  double mean = (double)E / nb;
  long long Cwant = (long long)(mean * 1.10) + (long long)(BIN_BLOCKS * PAD / 2) + 512;
  size_t budget = ws_size > fixed ? ws_size - fixed - 4096 : 0;
  long long Cbud = (long long)(budget / ((size_t)nb * 4));
  long long Cll = Cwant < Cbud ? Cwant : Cbud;
  if (Cll > SORT_STAGE) Cll = SORT_STAGE;
  int C = (int)(Cll & ~(long long)(PAD - 1));

  char* p = (char*)d_ws;
  int*    payload = (int*)p;    p += al((size_t)nb * C * 4);
  int*    off_g   = (int*)p;    p += sz_off;
  float*  y       = (float*)p;  p += sz_y;
  float4* G       = (float4*)p; p += sz_G;
  int*    gcur    = (int*)p;    p += sz_gc;

  hipMemsetAsync(gcur, 0, (size_t)nb * 4, stream);

  int chunk = (int)(((long long)E + BIN_BLOCKS - 1) / BIN_BLOCKS);
  chunk = (chunk + 3) & ~3;  // keep int4 alignment per block

  k_bin<<<BIN_BLOCKS, BIN_THREADS, 0, stream>>>(src, dst, E, chunk, nb, C,
                                                gcur, payload);
  k_sort<<<nb, 256, 0, stream>>>(payload, gcur, C, n, x, off_g, y);
  k_reduce1<<<nb, 256, 0, stream>>>(payload, off_g, C, n, y, W1, b1, W2, G);
  k_reduce2<<<nb, 256, 0, stream>>>(payload, off_g, C, n, G, b2,
                                    (float4*)d_out);
}

// Round 5
// 797.086 us; speedup vs baseline: 5.8753x; 1.0922x over previous
//
#include <hip/hip_runtime.h>

// 2-layer GCNConv, N=500K, E=16M, Cin=1, Cout=4, fp32.
//
// Round-4 findings: k_bin latency-bound (VALUBusy 2.3%, occ 44%, 1 block/CU).
// WRITE_SIZE ~27B/scattered-4B-store confirms ~32B write sectors.
// This round: (1) k_bin 512 blocks + PAD=8 (32B exclusive granules, same
// inflation budget) + unroll; (2) k_sort stores packed (src<<8|node) sorted,
// so reduces are wave-cooperative: coalesced seg loads + shfl segmented scan,
// LDS add only at segment ends (removes per-lane scatter of seg reads and
// Poisson imbalance); (3) unrolled sort place loop.

#define BIN_BLOCKS 512
#define BIN_THREADS 1024
#define PAD 8            // pad reservations to 8 slots = 32 B granules
#define MAXNB 2048       // supports n <= 524288
#define SORT_STAGE 12032 // ints staged in LDS by k_sort (47 KB); C <= this

__global__ __launch_bounds__(BIN_THREADS) void k_bin(
    const int* __restrict__ src, const int* __restrict__ dst, int E,
    int chunk, int nb, int C, int* __restrict__ gcur,
    int* __restrict__ payload) {
  __shared__ int hist[MAXNB];
  __shared__ int lbase[MAXNB];
  const int tid = threadIdx.x;
  const long long e0 = (long long)blockIdx.x * chunk;
  long long rem = (long long)E - e0;
  int lim = rem < 0 ? 0 : (rem < chunk ? (int)rem : chunk);

  for (int j = tid; j < nb; j += BIN_THREADS) hist[j] = 0;
  __syncthreads();

  const int* dch = dst + e0;
  const int* sch = src + e0;
  const int nv = lim >> 2;

  // pass 1: local histogram (LDS atomics, fire-and-forget)
#pragma unroll 2
  for (int k = tid; k < nv; k += BIN_THREADS) {
    int4 d = reinterpret_cast<const int4*>(dch)[k];
    atomicAdd(&hist[d.x >> 8], 1);
    atomicAdd(&hist[d.y >> 8], 1);
    atomicAdd(&hist[d.z >> 8], 1);
    atomicAdd(&hist[d.w >> 8], 1);
  }
  for (int k = (nv << 2) + tid; k < lim; k += BIN_THREADS)
    atomicAdd(&hist[dch[k] >> 8], 1);
  __syncthreads();

  // reserve padded ranges: one global fetch-add per (block,bucket)
  for (int j = tid; j < nb; j += BIN_THREADS) {
    int c = hist[j];
    lbase[j] = c ? atomicAdd(&gcur[j], (c + PAD - 1) & ~(PAD - 1)) : 0;
    hist[j] = 0;  // reuse as local rank cursor
  }
  __syncthreads();

  // pass 2: place edges (normal cached stores)
#pragma unroll 2
  for (int k = tid; k < nv; k += BIN_THREADS) {
    int4 d = reinterpret_cast<const int4*>(dch)[k];
    int4 s = reinterpret_cast<const int4*>(sch)[k];
    int b0 = d.x >> 8, b1 = d.y >> 8, b2 = d.z >> 8, b3 = d.w >> 8;
    int r0 = atomicAdd(&hist[b0], 1) + lbase[b0];
    int r1 = atomicAdd(&hist[b1], 1) + lbase[b1];
    int r2 = atomicAdd(&hist[b2], 1) + lbase[b2];
    int r3 = atomicAdd(&hist[b3], 1) + lbase[b3];
    if (r0 < C) payload[(long long)b0 * C + r0] = (s.x << 8) | (d.x & 255);
    if (r1 < C) payload[(long long)b1 * C + r1] = (s.y << 8) | (d.y & 255);
    if (r2 < C) payload[(long long)b2 * C + r2] = (s.z << 8) | (d.z & 255);
    if (r3 < C) payload[(long long)b3 * C + r3] = (s.w << 8) | (d.w & 255);
  }
  for (int k = (nv << 2) + tid; k < lim; k += BIN_THREADS) {
    int d = dch[k], s = sch[k];
    int bk = d >> 8;
    int r = atomicAdd(&hist[bk], 1) + lbase[bk];
    if (r < C) payload[(long long)bk * C + r] = (s << 8) | (d & 255);
  }
  __syncthreads();

  // sentinel-fill pad slots of this block's ranges
  for (int j = tid; j < nb; j += BIN_THREADS) {
    int c = hist[j];
    if (c) {
      int pc = (c + PAD - 1) & ~(PAD - 1);
      long long base = (long long)j * C;
      for (int k = lbase[j] + c; k < lbase[j] + pc; ++k)
        if (k < C) payload[base + k] = -1;
    }
  }
}

// Per-bucket in-LDS counting sort to node granularity (in-place on the
// global segment, keeps packed (src<<8|node)). hist == degree -> y = dinv*x.
__global__ __launch_bounds__(256) void k_sort(
    int* __restrict__ payload, const int* __restrict__ gcur, int C,
    int n, const float* __restrict__ x,
    int* __restrict__ off_g, float* __restrict__ y) {
  __shared__ int stage[SORT_STAGE];
  __shared__ int hist[256];
  __shared__ int sbuf[2][256];
  __shared__ int cur[256];
  const int b = blockIdx.x, t = threadIdx.x;
  hist[t] = 0;
  __syncthreads();

  int* seg = payload + (long long)b * C;
  const int L = min(gcur[b], C);
  const int nv = L >> 2;

  // stage segment into LDS + build per-node histogram
#pragma unroll 2
  for (int k = t; k < nv; k += 256) {
    int4 p = reinterpret_cast<const int4*>(seg)[k];
    reinterpret_cast<int4*>(stage)[k] = p;
    if (p.x >= 0) atomicAdd(&hist[p.x & 255], 1);
    if (p.y >= 0) atomicAdd(&hist[p.y & 255], 1);
    if (p.z >= 0) atomicAdd(&hist[p.z & 255], 1);
    if (p.w >= 0) atomicAdd(&hist[p.w & 255], 1);
  }
  for (int k = (nv << 2) + t; k < L; k += 256) {
    int p = seg[k];
    stage[k] = p;
    if (p >= 0) atomicAdd(&hist[p & 255], 1);
  }
  __syncthreads();

  // exclusive scan of hist (Hillis-Steele, double buffer)
  sbuf[0][t] = hist[t];
  __syncthreads();
  int pi = 0;
  for (int d = 1; d < 256; d <<= 1) {
    int v = sbuf[pi][t];
    if (t >= d) v += sbuf[pi][t - d];
    sbuf[pi ^ 1][t] = v;
    pi ^= 1;
    __syncthreads();
  }
  const int inc = sbuf[pi][t];
  const int exc = inc - hist[t];
  cur[t] = exc;
  off_g[b * 257 + t] = exc;
  if (t == 255) off_g[b * 257 + 256] = inc;

  const int i = (b << 8) + t;
  if (i < n) y[i] = rsqrtf((float)(hist[t] + 1)) * x[i];
  __syncthreads();

  // place: node-sorted packed edges back into the global segment
#pragma unroll 4
  for (int k = t; k < L; k += 256) {
    int p = stage[k];
    if (p >= 0) {
      int pos = atomicAdd(&cur[p & 255], 1);
      seg[pos] = p;  // keep packed (src<<8|node)
    }
  }
}

// Wave-cooperative segmented sum of y[src] per node; emit
// G[i] = dinv_i * (relu(s_i*W1 + b1) @ W2).
__global__ __launch_bounds__(256) void k_reduce1(
    const int* __restrict__ payload, const int* __restrict__ off_g, int C,
    int n, const float* __restrict__ y,
    const float* __restrict__ W1, const float* __restrict__ b1,
    const float* __restrict__ W2, float4* __restrict__ G) {
  __shared__ float S[256];
  const int b = blockIdx.x, t = threadIdx.x;
  S[t] = 0.0f;
  __syncthreads();
  const int L = off_g[b * 257 + 256];
  const int* seg = payload + (long long)b * C;
  const int lane = t & 63;

  for (int base = t - lane; base < L; base += 256) {
    int k = base + lane;
    bool valid = k < L;
    int p = valid ? seg[k] : 0;          // coalesced
    int m = valid ? (p & 255) : 999;
    float v = valid ? y[p >> 8] : 0.0f;  // gather
#pragma unroll
    for (int d = 1; d < 64; d <<= 1) {
      float vv = __shfl_up(v, d, 64);
      int mm = __shfl_up(m, d, 64);
      if (lane >= d && mm == m) v += vv;
    }
    int mn = __shfl_down(m, 1, 64);
    if ((lane == 63 || mn != m) && m < 256) atomicAdd(&S[m], v);
  }
  __syncthreads();

  const int i = (b << 8) + t;
  if (i < n) {
    int deg = off_g[b * 257 + t + 1] - off_g[b * 257 + t];
    float r = rsqrtf((float)(deg + 1));
    float si = r * (S[t] + y[i]);  // + self-loop
    float h0 = fmaxf(fmaf(si, W1[0], b1[0]), 0.0f);
    float h1 = fmaxf(fmaf(si, W1[1], b1[1]), 0.0f);
    float h2 = fmaxf(fmaf(si, W1[2], b1[2]), 0.0f);
    float h3 = fmaxf(fmaf(si, W1[3], b1[3]), 0.0f);
    G[i] = make_float4(
        r * (h0 * W2[0] + h1 * W2[4] + h2 * W2[8]  + h3 * W2[12]),
        r * (h0 * W2[1] + h1 * W2[5] + h2 * W2[9]  + h3 * W2[13]),
        r * (h0 * W2[2] + h1 * W2[6] + h2 * W2[10] + h3 * W2[14]),
        r * (h0 * W2[3] + h1 * W2[7] + h2 * W2[11] + h3 * W2[15]));
  }
}

// Wave-cooperative segmented float4 sum of G[src]; out = b2 + dinv*(sum+G[i]).
__global__ __launch_bounds__(256) void k_reduce2(
    const int* __restrict__ payload, const int* __restrict__ off_g, int C,
    int n, const float4* __restrict__ G, const float* __restrict__ b2,
    float4* __restrict__ out) {
  __shared__ float S[256][4];
  const int b = blockIdx.x, t = threadIdx.x;
  S[t][0] = 0.0f; S[t][1] = 0.0f; S[t][2] = 0.0f; S[t][3] = 0.0f;
  __syncthreads();
  const int L = off_g[b * 257 + 256];
  const int* seg = payload + (long long)b * C;
  const int lane = t & 63;

  for (int base = t - lane; base < L; base += 256) {
    int k = base + lane;
    bool valid = k < L;
    int p = valid ? seg[k] : 0;  // coalesced
    int m = valid ? (p & 255) : 999;
    float4 v = valid ? G[p >> 8] : make_float4(0.f, 0.f, 0.f, 0.f);
#pragma unroll
    for (int d = 1; d < 64; d <<= 1) {
      float vx = __shfl_up(v.x, d, 64);
      float vy = __shfl_up(v.y, d, 64);
      float vz = __shfl_up(v.z, d, 64);
      float vw = __shfl_up(v.w, d, 64);
      int mm = __shfl_up(m, d, 64);
      if (lane >= d && mm == m) { v.x += vx; v.y += vy; v.z += vz; v.w += vw; }
    }
    int mn = __shfl_down(m, 1, 64);
    if ((lane == 63 || mn != m) && m < 256) {
      atomicAdd(&S[m][0], v.x);
      atomicAdd(&S[m][1], v.y);
      atomicAdd(&S[m][2], v.z);
      atomicAdd(&S[m][3], v.w);
    }
  }
  __syncthreads();

  const int i = (b << 8) + t;
  if (i < n) {
    int deg = off_g[b * 257 + t + 1] - off_g[b * 257 + t];
    float r = rsqrtf((float)(deg + 1));
    float4 gi = G[i];
    out[i] = make_float4(b2[0] + r * (S[t][0] + gi.x),
                         b2[1] + r * (S[t][1] + gi.y),
                         b2[2] + r * (S[t][2] + gi.z),
                         b2[3] + r * (S[t][3] + gi.w));
  }
}

extern "C" void kernel_launch(void* const* d_in, const int* in_sizes, int n_in,
                              void* d_out, int out_size, void* d_ws, size_t ws_size,
                              hipStream_t stream) {
  const float* x  = (const float*)d_in[0];
  const int*   ei = (const int*)d_in[1];
  const float* W1 = (const float*)d_in[2];
  const float* b1 = (const float*)d_in[3];
  const float* W2 = (const float*)d_in[4];
  const float* b2 = (const float*)d_in[5];

  const int n = in_sizes[0];
  const int E = in_sizes[1] / 2;
  const int* src = ei;
  const int* dst = ei + E;

  const int nb = (n + 255) >> 8;  // buckets of 256 nodes (nb <= MAXNB)
  auto al = [](size_t v) { return (v + 255) & ~(size_t)255; };

  const size_t nn = (size_t)n;
  size_t sz_off = al((size_t)nb * 257 * 4);
  size_t sz_y   = al(nn * 4);
  size_t sz_G   = al(nn * 16);
  size_t sz_gc  = al((size_t)nb * 4);
  size_t fixed = sz_off + sz_y + sz_G + sz_gc;

  // bucket capacity: mean + expected pad inflation + slack, capped by
  // workspace budget and the k_sort LDS stage capacity
  double mean = (double)E / nb;
  long long Cwant = (long long)(mean * 1.10) + (long long)(BIN_BLOCKS * PAD / 2) + 512;
  size_t budget = ws_size > fixed ? ws_size - fixed - 4096 : 0;
  long long Cbud = (long long)(budget / ((size_t)nb * 4));
  long long Cll = Cwant < Cbud ? Cwant : Cbud;
  if (Cll > SORT_STAGE) Cll = SORT_STAGE;
  int C = (int)(Cll & ~(long long)(PAD - 1));

  char* p = (char*)d_ws;
  int*    payload = (int*)p;    p += al((size_t)nb * C * 4);
  int*    off_g   = (int*)p;    p += sz_off;
  float*  y       = (float*)p;  p += sz_y;
  float4* G       = (float4*)p; p += sz_G;
  int*    gcur    = (int*)p;    p += sz_gc;

  hipMemsetAsync(gcur, 0, (size_t)nb * 4, stream);

  int chunk = (int)(((long long)E + BIN_BLOCKS - 1) / BIN_BLOCKS);
  chunk = (chunk + 3) & ~3;  // keep int4 alignment per block

  k_bin<<<BIN_BLOCKS, BIN_THREADS, 0, stream>>>(src, dst, E, chunk, nb, C,
                                                gcur, payload);
  k_sort<<<nb, 256, 0, stream>>>(payload, gcur, C, n, x, off_g, y);
  k_reduce1<<<nb, 256, 0, stream>>>(payload, off_g, C, n, y, W1, b1, W2, G);
  k_reduce2<<<nb, 256, 0, stream>>>(payload, off_g, C, n, G, b2,
                                    (float4*)d_out);
}

// Round 6
// 538.142 us; speedup vs baseline: 8.7024x; 1.4812x over previous
//
#include <hip/hip_runtime.h>

// 2-layer GCNConv, N=500K, E=16M, Cin=1, Cout=4, fp32.
//
// Round-5 finding: k_bin was bound by partial-sector HBM writes (16M
// scattered 4B stores -> 464 MB @ ~1.5 TB/s). This round: two-level
// LDS-staged multisplit so ALL payload writes are coalesced full-line
// bursts (k_bin1: 245 coarse buckets of 2048 nodes; k_bin2: 8 fine/coarse
// -> 256-node buckets, exact counts, no sentinels). Reduces now gather
// 8B ds=(r,s) from a 4MB array; layer-2 message computed in registers.

#define B1_BLOCKS 512
#define B1_THREADS 1024
#define TILE1 16384
#define B2_THREADS 1024
#define TILE2 16384
#define MAXNB1 256       // coarse buckets (2048 nodes); needs n <= 524288
#define SORT_STAGE 12032 // ints staged in LDS by k_sort; C2 <= this
// fallback (round-5 flat binning) constants
#define FB_BLOCKS 512
#define FB_THREADS 1024
#define FB_PAD 8
#define MAXNBF 2048

// ---------------- pass 1: coarse split (LDS-staged, coalesced flush) -------
__global__ __launch_bounds__(B1_THREADS) void k_bin1(
    const int* __restrict__ src, const int* __restrict__ dst, int E,
    int chunk, int nb1, int C1, int* __restrict__ gcur1,
    int* __restrict__ pay1) {
  __shared__ int out[TILE1];
  __shared__ int hist[MAXNB1], toff[MAXNB1], wcur[MAXNB1], gb[MAXNB1];
  __shared__ int sbuf[2][MAXNB1];
  const int tid = threadIdx.x;
  const long long e0 = (long long)blockIdx.x * chunk;
  long long reml = (long long)E - e0;
  const int lim = reml < 0 ? 0 : (reml < chunk ? (int)reml : chunk);
  const int* dch = dst + e0;
  const int* sch = src + e0;

  for (int tb = 0; tb < lim; tb += TILE1) {
    const int tcnt = min(TILE1, lim - tb);
    const int nv = tcnt >> 2;
    for (int j = tid; j < MAXNB1; j += B1_THREADS) hist[j] = 0;
    __syncthreads();

    // phase A: tile histogram of coarse keys
    const int* dt = dch + tb;
    for (int k = tid; k < nv; k += B1_THREADS) {
      int4 d = reinterpret_cast<const int4*>(dt)[k];
      atomicAdd(&hist[d.x >> 11], 1);
      atomicAdd(&hist[d.y >> 11], 1);
      atomicAdd(&hist[d.z >> 11], 1);
      atomicAdd(&hist[d.w >> 11], 1);
    }
    for (int k = (nv << 2) + tid; k < tcnt; k += B1_THREADS)
      atomicAdd(&hist[dt[k] >> 11], 1);
    __syncthreads();

    // phase B: exclusive scan (256-wide) + exact global range reservation
    if (tid < MAXNB1) sbuf[0][tid] = hist[tid];
    __syncthreads();
    int pi = 0;
    for (int dd = 1; dd < MAXNB1; dd <<= 1) {
      if (tid < MAXNB1) {
        int v = sbuf[pi][tid];
        if (tid >= dd) v += sbuf[pi][tid - dd];
        sbuf[pi ^ 1][tid] = v;
      }
      pi ^= 1;
      __syncthreads();
    }
    if (tid < MAXNB1) {
      int c = hist[tid];
      int exc = sbuf[pi][tid] - c;
      toff[tid] = exc;
      wcur[tid] = exc;
      gb[tid] = c ? atomicAdd(&gcur1[tid], c) : 0;
    }
    __syncthreads();

    // phase C: rank + place packed (src<<11 | dst&2047) into LDS out
    const int* st = sch + tb;
    for (int k = tid; k < nv; k += B1_THREADS) {
      int4 d = reinterpret_cast<const int4*>(dt)[k];
      int4 s = reinterpret_cast<const int4*>(st)[k];
      int r0 = atomicAdd(&wcur[d.x >> 11], 1);
      int r1 = atomicAdd(&wcur[d.y >> 11], 1);
      int r2 = atomicAdd(&wcur[d.z >> 11], 1);
      int r3 = atomicAdd(&wcur[d.w >> 11], 1);
      out[r0] = (s.x << 11) | (d.x & 2047);
      out[r1] = (s.y << 11) | (d.y & 2047);
      out[r2] = (s.z << 11) | (d.z & 2047);
      out[r3] = (s.w << 11) | (d.w & 2047);
    }
    for (int k = (nv << 2) + tid; k < tcnt; k += B1_THREADS) {
      int d = dt[k], s = st[k];
      int r = atomicAdd(&wcur[d >> 11], 1);
      out[r] = (s << 11) | (d & 2047);
    }
    __syncthreads();

    // phase D: wave-per-bucket coalesced copy LDS -> global
    const int wv = tid >> 6, lane = tid & 63;
    for (int j = wv; j < nb1; j += 16) {
      const int c = wcur[j] - toff[j];
      if (!c) continue;
      const int gbase = gb[j];
      const long long pbase = (long long)j * C1;
      for (int q = lane; q < c; q += 64) {
        int gi = gbase + q;
        if (gi < C1) pay1[pbase + gi] = out[toff[j] + q];
      }
    }
    __syncthreads();
  }
}

// ---------------- pass 2: fine split (8 buckets per coarse) ----------------
__global__ __launch_bounds__(B2_THREADS) void k_bin2(
    const int* __restrict__ pay1, const int* __restrict__ gcur1, int C1,
    int C2, int* __restrict__ gcur2, int* __restrict__ pay2) {
  __shared__ int out[TILE2];
  __shared__ int hist[8], toff9[9], wcur[8], gb[8];
  const int cb = blockIdx.x >> 1;
  const int half = blockIdx.x & 1;
  const int tid = threadIdx.x;
  const int Lc = min(gcur1[cb], C1);
  int mid = ((Lc >> 1) + 3) & ~3;
  if (mid > Lc) mid = Lc;
  const int h0 = half ? mid : 0;
  const int h1 = half ? Lc : mid;
  const int* seg = pay1 + (long long)cb * C1;

  for (int tb = h0; tb < h1; tb += TILE2) {
    const int tcnt = min(TILE2, h1 - tb);
    const int nv = tcnt >> 2;
    if (tid < 8) hist[tid] = 0;
    __syncthreads();
    const int* pt = seg + tb;

    for (int k = tid; k < nv; k += B2_THREADS) {
      int4 p = reinterpret_cast<const int4*>(pt)[k];
      atomicAdd(&hist[(p.x >> 8) & 7], 1);
      atomicAdd(&hist[(p.y >> 8) & 7], 1);
      atomicAdd(&hist[(p.z >> 8) & 7], 1);
      atomicAdd(&hist[(p.w >> 8) & 7], 1);
    }
    for (int k = (nv << 2) + tid; k < tcnt; k += B2_THREADS)
      atomicAdd(&hist[(pt[k] >> 8) & 7], 1);
    __syncthreads();

    if (tid == 0) {
      int run = 0;
      for (int j = 0; j < 8; ++j) { toff9[j] = run; run += hist[j]; }
      toff9[8] = run;
    }
    __syncthreads();
    if (tid < 8) {
      wcur[tid] = toff9[tid];
      gb[tid] = hist[tid] ? atomicAdd(&gcur2[cb * 8 + tid], hist[tid]) : 0;
    }
    __syncthreads();

    for (int k = tid; k < nv; k += B2_THREADS) {
      int4 p = reinterpret_cast<const int4*>(pt)[k];
      out[atomicAdd(&wcur[(p.x >> 8) & 7], 1)] = ((p.x >> 11) << 8) | (p.x & 255);
      out[atomicAdd(&wcur[(p.y >> 8) & 7], 1)] = ((p.y >> 11) << 8) | (p.y & 255);
      out[atomicAdd(&wcur[(p.z >> 8) & 7], 1)] = ((p.z >> 11) << 8) | (p.z & 255);
      out[atomicAdd(&wcur[(p.w >> 8) & 7], 1)] = ((p.w >> 11) << 8) | (p.w & 255);
    }
    for (int k = (nv << 2) + tid; k < tcnt; k += B2_THREADS) {
      int p = pt[k];
      out[atomicAdd(&wcur[(p >> 8) & 7], 1)] = ((p >> 11) << 8) | (p & 255);
    }
    __syncthreads();

    const int total = toff9[8];
    for (int q = tid; q < total; q += B2_THREADS) {
      int j = (q >= toff9[4]) ? 4 : 0;
      j += (q >= toff9[j + 2]) ? 2 : 0;
      j += (q >= toff9[j + 1]) ? 1 : 0;
      int o = gb[j] + (q - toff9[j]);
      if (o < C2) pay2[(long long)(cb * 8 + j) * C2 + o] = out[q];
    }
    __syncthreads();
  }
}

// ---------------- fallback flat binning (round-5, proven) ------------------
__global__ __launch_bounds__(FB_THREADS) void k_bin_flat(
    const int* __restrict__ src, const int* __restrict__ dst, int E,
    int chunk, int nbf, int C, int* __restrict__ gcur,
    int* __restrict__ payload) {
  __shared__ int hist[MAXNBF];
  __shared__ int lbase[MAXNBF];
  const int tid = threadIdx.x;
  const long long e0 = (long long)blockIdx.x * chunk;
  long long rem = (long long)E - e0;
  int lim = rem < 0 ? 0 : (rem < chunk ? (int)rem : chunk);
  for (int j = tid; j < nbf; j += FB_THREADS) hist[j] = 0;
  __syncthreads();
  const int* dch = dst + e0;
  const int* sch = src + e0;
  const int nv = lim >> 2;
  for (int k = tid; k < nv; k += FB_THREADS) {
    int4 d = reinterpret_cast<const int4*>(dch)[k];
    atomicAdd(&hist[d.x >> 8], 1);
    atomicAdd(&hist[d.y >> 8], 1);
    atomicAdd(&hist[d.z >> 8], 1);
    atomicAdd(&hist[d.w >> 8], 1);
  }
  for (int k = (nv << 2) + tid; k < lim; k += FB_THREADS)
    atomicAdd(&hist[dch[k] >> 8], 1);
  __syncthreads();
  for (int j = tid; j < nbf; j += FB_THREADS) {
    int c = hist[j];
    lbase[j] = c ? atomicAdd(&gcur[j], (c + FB_PAD - 1) & ~(FB_PAD - 1)) : 0;
    hist[j] = 0;
  }
  __syncthreads();
  for (int k = tid; k < nv; k += FB_THREADS) {
    int4 d = reinterpret_cast<const int4*>(dch)[k];
    int4 s = reinterpret_cast<const int4*>(sch)[k];
    int b0 = d.x >> 8, b1 = d.y >> 8, b2 = d.z >> 8, b3 = d.w >> 8;
    int r0 = atomicAdd(&hist[b0], 1) + lbase[b0];
    int r1 = atomicAdd(&hist[b1], 1) + lbase[b1];
    int r2 = atomicAdd(&hist[b2], 1) + lbase[b2];
    int r3 = atomicAdd(&hist[b3], 1) + lbase[b3];
    if (r0 < C) payload[(long long)b0 * C + r0] = (s.x << 8) | (d.x & 255);
    if (r1 < C) payload[(long long)b1 * C + r1] = (s.y << 8) | (d.y & 255);
    if (r2 < C) payload[(long long)b2 * C + r2] = (s.z << 8) | (d.z & 255);
    if (r3 < C) payload[(long long)b3 * C + r3] = (s.w << 8) | (d.w & 255);
  }
  for (int k = (nv << 2) + tid; k < lim; k += FB_THREADS) {
    int d = dch[k], s = sch[k];
    int bk = d >> 8;
    int r = atomicAdd(&hist[bk], 1) + lbase[bk];
    if (r < C) payload[(long long)bk * C + r] = (s << 8) | (d & 255);
  }
  __syncthreads();
  for (int j = tid; j < nbf; j += FB_THREADS) {
    int c = hist[j];
    if (c) {
      int pc = (c + FB_PAD - 1) & ~(FB_PAD - 1);
      long long base = (long long)j * C;
      for (int k = lbase[j] + c; k < lbase[j] + pc; ++k)
        if (k < C) payload[base + k] = -1;
    }
  }
}

// ---------------- per-bucket counting sort to node order -------------------
__global__ __launch_bounds__(256) void k_sort(
    int* __restrict__ payload, const int* __restrict__ gcur, int C,
    int n, const float* __restrict__ x,
    int* __restrict__ off_g, float* __restrict__ y) {
  __shared__ int stage[SORT_STAGE];
  __shared__ int hist[256];
  __shared__ int sbuf[2][256];
  __shared__ int cur[256];
  const int b = blockIdx.x, t = threadIdx.x;
  hist[t] = 0;
  __syncthreads();
  int* seg = payload + (long long)b * C;
  const int L = min(gcur[b], C);
  const int nv = L >> 2;
#pragma unroll 2
  for (int k = t; k < nv; k += 256) {
    int4 p = reinterpret_cast<const int4*>(seg)[k];
    reinterpret_cast<int4*>(stage)[k] = p;
    if (p.x >= 0) atomicAdd(&hist[p.x & 255], 1);
    if (p.y >= 0) atomicAdd(&hist[p.y & 255], 1);
    if (p.z >= 0) atomicAdd(&hist[p.z & 255], 1);
    if (p.w >= 0) atomicAdd(&hist[p.w & 255], 1);
  }
  for (int k = (nv << 2) + t; k < L; k += 256) {
    int p = seg[k];
    stage[k] = p;
    if (p >= 0) atomicAdd(&hist[p & 255], 1);
  }
  __syncthreads();
  sbuf[0][t] = hist[t];
  __syncthreads();
  int pi = 0;
  for (int d = 1; d < 256; d <<= 1) {
    int v = sbuf[pi][t];
    if (t >= d) v += sbuf[pi][t - d];
    sbuf[pi ^ 1][t] = v;
    pi ^= 1;
    __syncthreads();
  }
  const int inc = sbuf[pi][t];
  const int exc = inc - hist[t];
  cur[t] = exc;
  off_g[b * 257 + t] = exc;
  if (t == 255) off_g[b * 257 + 256] = inc;
  const int i = (b << 8) + t;
  if (i < n) y[i] = rsqrtf((float)(hist[t] + 1)) * x[i];
  __syncthreads();
#pragma unroll 4
  for (int k = t; k < L; k += 256) {
    int p = stage[k];
    if (p >= 0) {
      int pos = atomicAdd(&cur[p & 255], 1);
      seg[pos] = p;
    }
  }
}

// ---------------- layer-1 segmented sum -> ds = (dinv, s) ------------------
__global__ __launch_bounds__(256) void k_reduce1(
    const int* __restrict__ payload, const int* __restrict__ off_g, int C,
    int n, const float* __restrict__ y, float2* __restrict__ ds) {
  __shared__ float S[256];
  const int b = blockIdx.x, t = threadIdx.x;
  S[t] = 0.0f;
  __syncthreads();
  const int L = off_g[b * 257 + 256];
  const int* seg = payload + (long long)b * C;
  const int lane = t & 63;
  for (int base = t - lane; base < L; base += 256) {
    int k = base + lane;
    bool valid = k < L;
    int p = valid ? seg[k] : 0;
    int m = valid ? (p & 255) : 999;
    float v = valid ? y[p >> 8] : 0.0f;
#pragma unroll
    for (int d = 1; d < 64; d <<= 1) {
      float vv = __shfl_up(v, d, 64);
      int mm = __shfl_up(m, d, 64);
      if (lane >= d && mm == m) v += vv;
    }
    int mn = __shfl_down(m, 1, 64);
    if ((lane == 63 || mn != m) && m < 256) atomicAdd(&S[m], v);
  }
  __syncthreads();
  const int i = (b << 8) + t;
  if (i < n) {
    int deg = off_g[b * 257 + t + 1] - off_g[b * 257 + t];
    float r = rsqrtf((float)(deg + 1));
    ds[i] = make_float2(r, r * (S[t] + y[i]));
  }
}

// ---------------- layer-2: gather ds, compute message, segmented sum -------
__global__ __launch_bounds__(256) void k_reduce2(
    const int* __restrict__ payload, const int* __restrict__ off_g, int C,
    int n, const float2* __restrict__ ds,
    const float* __restrict__ W1, const float* __restrict__ b1,
    const float* __restrict__ W2, const float* __restrict__ b2,
    float4* __restrict__ out) {
  __shared__ float S0[256], S1[256], S2[256], S3[256];
  const int b = blockIdx.x, t = threadIdx.x;
  S0[t] = 0.f; S1[t] = 0.f; S2[t] = 0.f; S3[t] = 0.f;
  __syncthreads();
  const float w10 = W1[0], w11 = W1[1], w12 = W1[2], w13 = W1[3];
  const float c10 = b1[0], c11 = b1[1], c12 = b1[2], c13 = b1[3];
  float w2[16];
#pragma unroll
  for (int k = 0; k < 16; ++k) w2[k] = W2[k];

  const int L = off_g[b * 257 + 256];
  const int* seg = payload + (long long)b * C;
  const int lane = t & 63;
  for (int base = t - lane; base < L; base += 256) {
    int k = base + lane;
    bool valid = k < L;
    int p = valid ? seg[k] : 0;
    int m = valid ? (p & 255) : 999;
    float2 v = valid ? ds[p >> 8] : make_float2(0.f, 0.f);
    float r = valid ? v.x : 0.0f;  // r=0 zeroes the whole message
    float s = v.y;
    float h0 = fmaxf(fmaf(s, w10, c10), 0.f);
    float h1 = fmaxf(fmaf(s, w11, c11), 0.f);
    float h2 = fmaxf(fmaf(s, w12, c12), 0.f);
    float h3 = fmaxf(fmaf(s, w13, c13), 0.f);
    float gx = r * (h0 * w2[0] + h1 * w2[4] + h2 * w2[8]  + h3 * w2[12]);
    float gy = r * (h0 * w2[1] + h1 * w2[5] + h2 * w2[9]  + h3 * w2[13]);
    float gz = r * (h0 * w2[2] + h1 * w2[6] + h2 * w2[10] + h3 * w2[14]);
    float gw = r * (h0 * w2[3] + h1 * w2[7] + h2 * w2[11] + h3 * w2[15]);
#pragma unroll
    for (int d = 1; d < 64; d <<= 1) {
      float ax = __shfl_up(gx, d, 64);
      float ay = __shfl_up(gy, d, 64);
      float az = __shfl_up(gz, d, 64);
      float aw = __shfl_up(gw, d, 64);
      int mm = __shfl_up(m, d, 64);
      if (lane >= d && mm == m) { gx += ax; gy += ay; gz += az; gw += aw; }
    }
    int mn = __shfl_down(m, 1, 64);
    if ((lane == 63 || mn != m) && m < 256) {
      atomicAdd(&S0[m], gx);
      atomicAdd(&S1[m], gy);
      atomicAdd(&S2[m], gz);
      atomicAdd(&S3[m], gw);
    }
  }
  __syncthreads();
  const int i = (b << 8) + t;
  if (i < n) {
    float2 v = ds[i];
    float r = v.x, s = v.y;
    float h0 = fmaxf(fmaf(s, w10, c10), 0.f);
    float h1 = fmaxf(fmaf(s, w11, c11), 0.f);
    float h2 = fmaxf(fmaf(s, w12, c12), 0.f);
    float h3 = fmaxf(fmaf(s, w13, c13), 0.f);
    float gx = r * (h0 * w2[0] + h1 * w2[4] + h2 * w2[8]  + h3 * w2[12]);
    float gy = r * (h0 * w2[1] + h1 * w2[5] + h2 * w2[9]  + h3 * w2[13]);
    float gz = r * (h0 * w2[2] + h1 * w2[6] + h2 * w2[10] + h3 * w2[14]);
    float gw = r * (h0 * w2[3] + h1 * w2[7] + h2 * w2[11] + h3 * w2[15]);
    out[i] = make_float4(b2[0] + r * (S0[t] + gx),
                         b2[1] + r * (S1[t] + gy),
                         b2[2] + r * (S2[t] + gz),
                         b2[3] + r * (S3[t] + gw));
  }
}

extern "C" void kernel_launch(void* const* d_in, const int* in_sizes, int n_in,
                              void* d_out, int out_size, void* d_ws, size_t ws_size,
                              hipStream_t stream) {
  const float* x  = (const float*)d_in[0];
  const int*   ei = (const int*)d_in[1];
  const float* W1 = (const float*)d_in[2];
  const float* b1 = (const float*)d_in[3];
  const float* W2 = (const float*)d_in[4];
  const float* b2 = (const float*)d_in[5];

  const int n = in_sizes[0];
  const int E = in_sizes[1] / 2;
  const int* src = ei;
  const int* dst = ei + E;

  const int nbf = (n + 255) >> 8;    // fine buckets (256 nodes)
  const int nb1 = (n + 2047) >> 11;  // coarse buckets (2048 nodes)
  auto al = [](size_t v) { return (v + 255) & ~(size_t)255; };

  const size_t nn = (size_t)n;
  size_t sz_off = al((size_t)nbf * 257 * 4);
  size_t sz_y   = al(nn * 4);
  size_t sz_ds  = al(nn * 8);
  size_t sz_gc  = al(((size_t)nb1 + nbf) * 4);
  size_t fixed = sz_off + sz_y + sz_ds + sz_gc;

  // main-path capacities (exact counts + Poisson slack)
  long long mean1 = (long long)E / (nb1 > 0 ? nb1 : 1);
  long long C1ll = ((mean1 + 2048 + 1024) + 15) & ~15LL;
  long long mean2 = (long long)E / nbf;
  long long C2ll = ((mean2 + 1024) + 15) & ~15LL;
  size_t need_main = fixed + al((size_t)nb1 * C1ll * 4) + al((size_t)nbf * C2ll * 4);
  const bool main_ok = (n <= 524288) && (nb1 <= MAXNB1) && (nbf <= MAXNBF) &&
                       (C2ll <= SORT_STAGE) && (need_main <= ws_size);

  if (main_ok) {
    const int C1 = (int)C1ll, C2 = (int)C2ll;
    char* p = (char*)d_ws;
    int*    pay1  = (int*)p;    p += al((size_t)nb1 * C1 * 4);
    int*    pay2  = (int*)p;    p += al((size_t)nbf * C2 * 4);
    int*    gcur1 = (int*)p;    // nb1 + nbf contiguous
    int*    gcur2 = gcur1 + nb1;
    p += sz_gc;
    int*    off_g = (int*)p;    p += sz_off;
    float*  y     = (float*)p;  p += sz_y;
    float2* ds    = (float2*)p; p += sz_ds;

    hipMemsetAsync(gcur1, 0, ((size_t)nb1 + nbf) * 4, stream);

    int chunk = (int)(((long long)E + B1_BLOCKS - 1) / B1_BLOCKS);
    chunk = (chunk + 3) & ~3;

    k_bin1<<<B1_BLOCKS, B1_THREADS, 0, stream>>>(src, dst, E, chunk, nb1, C1,
                                                 gcur1, pay1);
    k_bin2<<<nb1 * 2, B2_THREADS, 0, stream>>>(pay1, gcur1, C1, C2, gcur2,
                                               pay2);
    k_sort<<<nbf, 256, 0, stream>>>(pay2, gcur2, C2, n, x, off_g, y);
    k_reduce1<<<nbf, 256, 0, stream>>>(pay2, off_g, C2, n, y, ds);
    k_reduce2<<<nbf, 256, 0, stream>>>(pay2, off_g, C2, n, ds, W1, b1, W2, b2,
                                       (float4*)d_out);
    return;
  }

  // ---- fallback: round-5 flat binning into fine buckets ----
  {
    double mean = (double)E / nbf;
    long long Cwant = (long long)(mean * 1.10) +
                      (long long)(FB_BLOCKS * FB_PAD / 2) + 512;
    size_t budget = ws_size > fixed ? ws_size - fixed - 4096 : 0;
    long long Cbud = (long long)(budget / ((size_t)nbf * 4));
    long long Cll = Cwant < Cbud ? Cwant : Cbud;
    if (Cll > SORT_STAGE) Cll = SORT_STAGE;
    int C = (int)(Cll & ~(long long)(FB_PAD - 1));

    char* p = (char*)d_ws;
    int*    pay2  = (int*)p;    p += al((size_t)nbf * C * 4);
    int*    gcur  = (int*)p;    p += sz_gc;
    int*    off_g = (int*)p;    p += sz_off;
    float*  y     = (float*)p;  p += sz_y;
    float2* ds    = (float2*)p; p += sz_ds;

    hipMemsetAsync(gcur, 0, (size_t)nbf * 4, stream);

    int chunk = (int)(((long long)E + FB_BLOCKS - 1) / FB_BLOCKS);
    chunk = (chunk + 3) & ~3;

    k_bin_flat<<<FB_BLOCKS, FB_THREADS, 0, stream>>>(src, dst, E, chunk, nbf,
                                                     C, gcur, pay2);
    k_sort<<<nbf, 256, 0, stream>>>(pay2, gcur, C, n, x, off_g, y);
    k_reduce1<<<nbf, 256, 0, stream>>>(pay2, off_g, C, n, y, ds);
    k_reduce2<<<nbf, 256, 0, stream>>>(pay2, off_g, C, n, ds, W1, b1, W2, b2,
                                       (float4*)d_out);
  }
}